// Round 1
// baseline (1101.729 us; speedup 1.0000x reference)
//
#include <hip/hip_runtime.h>

#define N_NODES 50000
#define N_EDGES 800000
#define D 64
#define ET_PAD 68  // 64 + 4: keeps float4 LDS reads 16B-aligned, bounds staging conflicts

// ---------------------------------------------------------------------------
// Fold small weight matmuls (all 64-col, rows: WA 64, WB 128, WC 64, WD 64).
//   WA = W_n2e_u @ W_e2e[64:128]          (for a = X@WA)
//   WB = W_n2e_v @ W_e2e[64:128]  (128x64) (for b = S@WB[:64] + X@WB[64:])
//   WC = W_n2n_u @ Wv3                     (for XC = X@WC)
//   WD = W_e2n   @ Wv3                     (per-edge E@WD into segment sum)
// where Wv3 = W_n2n_v[128:192].
// ---------------------------------------------------------------------------
__global__ void fold_weights(const float* __restrict__ w_n2n_u,
                             const float* __restrict__ w_n2n_v,
                             const float* __restrict__ w_e2n,
                             const float* __restrict__ w_n2e_u,
                             const float* __restrict__ w_n2e_v,
                             const float* __restrict__ w_e2e,
                             float* __restrict__ WA, float* __restrict__ WB,
                             float* __restrict__ WC, float* __restrict__ WD) {
    int j = threadIdx.x;      // 0..63 output column
    int r = blockIdx.x;       // 0..319 output row across the 4 matrices
    const float* Ebot = w_e2e + 64 * 64;      // rows 64..127 of weight_e2e
    const float* Wv3  = w_n2n_v + 128 * 64;   // rows 128..191 of weight_n2n_v
    float acc = 0.f;
    if (r < 64) {
        for (int k = 0; k < 64; ++k) acc = fmaf(w_n2e_u[r * 64 + k], Ebot[k * 64 + j], acc);
        WA[r * 64 + j] = acc;
    } else if (r < 192) {
        int i = r - 64;
        for (int k = 0; k < 64; ++k) acc = fmaf(w_n2e_v[i * 64 + k], Ebot[k * 64 + j], acc);
        WB[i * 64 + j] = acc;
    } else if (r < 256) {
        int i = r - 192;
        for (int k = 0; k < 64; ++k) acc = fmaf(w_n2n_u[i * 64 + k], Wv3[k * 64 + j], acc);
        WC[i * 64 + j] = acc;
    } else {
        int i = r - 256;
        for (int k = 0; k < 64; ++k) acc = fmaf(w_e2n[i * 64 + k], Wv3[k * 64 + j], acc);
        WD[i * 64 + j] = acc;
    }
}

// ---------------------------------------------------------------------------
// Per-node precompute: one wave per node, lane = output column.
//   XC = X@WC, a = X@WA, b = S@WB_top + X@WB_bot,
//   hbase = S@Wv1 + X@Wv2 + bias_n  (written straight into d_out's h section)
// Weights read from global (L1-resident, wave-uniform k → coalesced per-j).
// ---------------------------------------------------------------------------
__global__ __launch_bounds__(256) void node_pre(
    const float* __restrict__ S, const float* __restrict__ X,
    const float* __restrict__ WA, const float* __restrict__ WB,
    const float* __restrict__ WC,
    const float* __restrict__ w_n2n_v, const float* __restrict__ bias_n,
    float* __restrict__ XC, float* __restrict__ a, float* __restrict__ b,
    float* __restrict__ hbase) {
    int wave = (blockIdx.x * blockDim.x + threadIdx.x) >> 6;
    int lane = threadIdx.x & 63;
    if (wave >= N_NODES) return;
    const int n = wave;
    float x = X[(size_t)n * 64 + lane];
    float s = S[(size_t)n * 64 + lane];
    const float* Wv1 = w_n2n_v;
    const float* Wv2 = w_n2n_v + 64 * 64;
    float accXC = 0.f, accA = 0.f, accB = 0.f, accH = 0.f;
    #pragma unroll 8
    for (int k = 0; k < 64; ++k) {
        float xb = __shfl(x, k, 64);
        float sb = __shfl(s, k, 64);
        accXC = fmaf(xb, WC[k * 64 + lane], accXC);
        accA  = fmaf(xb, WA[k * 64 + lane], accA);
        accB  = fmaf(sb, WB[k * 64 + lane], accB);
        accB  = fmaf(xb, WB[(64 + k) * 64 + lane], accB);
        accH  = fmaf(sb, Wv1[k * 64 + lane], accH);
        accH  = fmaf(xb, Wv2[k * 64 + lane], accH);
    }
    XC[(size_t)n * 64 + lane] = accXC;
    a [(size_t)n * 64 + lane] = accA;
    b [(size_t)n * 64 + lane] = accB;
    hbase[(size_t)n * 64 + lane] = accH + bias_n[lane];
}

// ---------------------------------------------------------------------------
// Edge pass: 64 edges/block, 256 threads. Per thread: column j = t&63,
// edge group g = t>>6 handles 16 edges. Computes:
//   e_out[e] = E[e]@W1 + a[src] + b[dst] + bias_e      (written to d_out)
//   atomicAdd(hpre[dst], XC[src] + E[e]@WD)            (pre-projected seg-sum)
//   atomicAdd(deg[dst], 1)
// ---------------------------------------------------------------------------
__global__ __launch_bounds__(256) void edge_kernel(
    const float* __restrict__ E, const int* __restrict__ src,
    const int* __restrict__ dst,
    const float* __restrict__ w_e2e /* W1 = rows 0..63 */,
    const float* __restrict__ WD,
    const float* __restrict__ a, const float* __restrict__ b,
    const float* __restrict__ XC, const float* __restrict__ bias_e,
    float* __restrict__ e_out, float* __restrict__ hpre,
    float* __restrict__ deg) {
    __shared__ float sW1[64 * 64];
    __shared__ float sWD[64 * 64];
    __shared__ __align__(16) float sEt[64 * ET_PAD];  // transposed E tile [k][r]

    const int t = threadIdx.x;
    for (int i = t; i < 4096; i += 256) {
        sW1[i] = w_e2e[i];
        sWD[i] = WD[i];
    }
    const int e0 = blockIdx.x * 64;
    // stage E tile transposed; global reads coalesced (consecutive t -> consecutive k)
    #pragma unroll
    for (int i = 0; i < 16; ++i) {
        int idx = i * 256 + t;
        int r = idx >> 6, k = idx & 63;
        sEt[k * ET_PAD + r] = E[(size_t)(e0 + r) * 64 + k];
    }
    __syncthreads();

    const int j = t & 63;
    const int g = t >> 6;  // wave id: edges e0+g*16 .. e0+g*16+15

    float acc1[16], acc2[16];
    const float bj = bias_e[j];
    #pragma unroll
    for (int r = 0; r < 16; ++r) {
        int e = e0 + g * 16 + r;
        int is = src[e];
        int id = dst[e];
        acc1[r] = bj + a[(size_t)is * 64 + j] + b[(size_t)id * 64 + j];
        acc2[r] = XC[(size_t)is * 64 + j];
    }

    #pragma unroll
    for (int k = 0; k < 64; ++k) {
        float w1 = sW1[k * 64 + j];
        float wd = sWD[k * 64 + j];
        const float4* ep = (const float4*)&sEt[k * ET_PAD + g * 16];
        #pragma unroll
        for (int q = 0; q < 4; ++q) {
            float4 ev = ep[q];
            acc1[4 * q + 0] = fmaf(ev.x, w1, acc1[4 * q + 0]);
            acc2[4 * q + 0] = fmaf(ev.x, wd, acc2[4 * q + 0]);
            acc1[4 * q + 1] = fmaf(ev.y, w1, acc1[4 * q + 1]);
            acc2[4 * q + 1] = fmaf(ev.y, wd, acc2[4 * q + 1]);
            acc1[4 * q + 2] = fmaf(ev.z, w1, acc1[4 * q + 2]);
            acc2[4 * q + 2] = fmaf(ev.z, wd, acc2[4 * q + 2]);
            acc1[4 * q + 3] = fmaf(ev.w, w1, acc1[4 * q + 3]);
            acc2[4 * q + 3] = fmaf(ev.w, wd, acc2[4 * q + 3]);
        }
    }

    #pragma unroll
    for (int r = 0; r < 16; ++r) {
        int e = e0 + g * 16 + r;
        int id = dst[e];
        e_out[(size_t)e * 64 + j] = acc1[r];
        atomicAdd(&hpre[(size_t)id * 64 + j], acc2[r]);
    }
    if (j == 0) {
        for (int r = 0; r < 16; ++r) {
            int e = e0 + g * 16 + r;
            atomicAdd(&deg[dst[e]], 1.0f);
        }
    }
}

// ---------------------------------------------------------------------------
// Final: h_out = hbase + hpre / max(deg,1)
// ---------------------------------------------------------------------------
__global__ void node_final(float* __restrict__ h_out,
                           const float* __restrict__ hpre,
                           const float* __restrict__ deg) {
    int i = blockIdx.x * blockDim.x + threadIdx.x;
    if (i < N_NODES * 64) {
        int n = i >> 6;
        float r = 1.0f / fmaxf(deg[n], 1.0f);
        h_out[i] += hpre[i] * r;
    }
}

extern "C" void kernel_launch(void* const* d_in, const int* in_sizes, int n_in,
                              void* d_out, int out_size, void* d_ws, size_t ws_size,
                              hipStream_t stream) {
    const float* S       = (const float*)d_in[0];   // Skipnode_in_feats [N,64]
    const float* X       = (const float*)d_in[1];   // node_in_feats     [N,64]
    const float* E       = (const float*)d_in[2];   // edge_in_feats     [E,64]
    const int*   src     = (const int*)  d_in[3];
    const int*   dst     = (const int*)  d_in[4];
    const float* w_n2n_u = (const float*)d_in[5];   // [64,64]
    const float* w_n2n_v = (const float*)d_in[6];   // [192,64]
    const float* w_e2n   = (const float*)d_in[7];   // [64,64]
    const float* bias_n  = (const float*)d_in[8];   // [64]
    const float* w_n2e_u = (const float*)d_in[9];   // [64,64]
    const float* w_n2e_v = (const float*)d_in[10];  // [128,64]
    const float* w_e2e   = (const float*)d_in[11];  // [128,64]
    const float* bias_e  = (const float*)d_in[12];  // [64]

    float* ws   = (float*)d_ws;
    const size_t ND = (size_t)N_NODES * 64;         // 3,200,000
    float* XC   = ws;                                // [N,64]
    float* a    = ws + ND;                           // [N,64]
    float* b    = ws + 2 * ND;                       // [N,64]
    float* hpre = ws + 3 * ND;                       // [N,64]  (zeroed)
    float* deg  = ws + 4 * ND;                       // [N]     (zeroed)
    float* WA   = ws + 4 * ND + N_NODES;             // 64x64
    float* WB   = WA + 64 * 64;                      // 128x64
    float* WC   = WB + 128 * 64;                     // 64x64
    float* WD   = WC + 64 * 64;                      // 64x64

    float* h_out = (float*)d_out;                    // [N,64]
    float* e_out = h_out + ND;                       // [E,64]

    // zero hpre + deg (contiguous)
    hipMemsetAsync(hpre, 0, (ND + N_NODES) * sizeof(float), stream);

    fold_weights<<<320, 64, 0, stream>>>(w_n2n_u, w_n2n_v, w_e2n, w_n2e_u,
                                         w_n2e_v, w_e2e, WA, WB, WC, WD);
    node_pre<<<(N_NODES * 64 + 255) / 256, 256, 0, stream>>>(
        S, X, WA, WB, WC, w_n2n_v, bias_n, XC, a, b, h_out);
    edge_kernel<<<N_EDGES / 64, 256, 0, stream>>>(
        E, src, dst, w_e2e, WD, a, b, XC, bias_e, e_out, hpre, deg);
    node_final<<<(N_NODES * 64 + 255) / 256, 256, 0, stream>>>(h_out, hpre, deg);
}

// Round 2
// 743.695 us; speedup vs baseline: 1.4814x; 1.4814x over previous
//
#include <hip/hip_runtime.h>

#define N_NODES 50000
#define N_EDGES 800000
#define D 64
#define ET_PAD 68   // 64+4: float4-aligned LDS reads; staging conflicts are ~8 µs total, accepted
#define NB 196      // ceil(50000/256) scan blocks

// ---------------------------------------------------------------------------
// Weight folding. Wbig[128][256] so node_pre is ONE GEMM [S|X](50Kx128)@Wbig:
//   cols   0.. 63: [Wv1;Wv2]              -> hbase (h_out before neigh term)
//   cols  64..127: [0; W_n2e_u@Ebot]      -> a
//   cols 128..191: [W_n2e_v@Ebot]         -> b
//   cols 192..255: [0; W_n2n_u@Wv3]       -> XC
// WD[64][64] = W_e2n@Wv3 (per-edge E@WD feeds the segment sum pre-projected).
// Ebot = w_e2e rows 64..127, Wv3 = w_n2n_v rows 128..191.
// ---------------------------------------------------------------------------
__global__ void fold_weights(const float* __restrict__ w_n2n_u,
                             const float* __restrict__ w_n2n_v,
                             const float* __restrict__ w_e2n,
                             const float* __restrict__ w_n2e_u,
                             const float* __restrict__ w_n2e_v,
                             float* __restrict__ w_e2e_dummy,
                             const float* __restrict__ w_e2e,
                             float* __restrict__ Wbig, float* __restrict__ WD) {
    int bidx = blockIdx.x;
    int j = threadIdx.x;
    const float* Ebot = w_e2e + 64 * 64;
    const float* Wv3  = w_n2n_v + 128 * 64;
    if (bidx < 512) {
        int k = bidx >> 2, q = bidx & 3;
        float v = 0.f;
        if (q == 0) {
            v = w_n2n_v[k * 64 + j];
        } else if (q == 1) {
            if (k >= 64) for (int t = 0; t < 64; ++t) v = fmaf(w_n2e_u[(k - 64) * 64 + t], Ebot[t * 64 + j], v);
        } else if (q == 2) {
            for (int t = 0; t < 64; ++t) v = fmaf(w_n2e_v[k * 64 + t], Ebot[t * 64 + j], v);
        } else {
            if (k >= 64) for (int t = 0; t < 64; ++t) v = fmaf(w_n2n_u[(k - 64) * 64 + t], Wv3[t * 64 + j], v);
        }
        Wbig[(size_t)k * 256 + q * 64 + j] = v;
    } else {
        int k = bidx - 512;
        float v = 0.f;
        for (int t = 0; t < 64; ++t) v = fmaf(w_e2n[k * 64 + t], Wv3[t * 64 + j], v);
        WD[k * 64 + j] = v;
    }
}

// ---------------------------------------------------------------------------
// node_pre: out[50000x256] = [S|X] @ Wbig, register-tiled GEMM.
// Block 256 thr, tile 64 rows x 64 cols, grid (782, 4). Epilogue scatters:
//   q0 -> h_out (+bias_n), q1 -> AX[.,2j] (a), q2 -> b, q3 -> AX[.,2j+1] (XC)
// a/XC interleaved so the edge kernel does ONE float2 gather per src.
// ---------------------------------------------------------------------------
__global__ __launch_bounds__(256) void node_pre(
    const float* __restrict__ S, const float* __restrict__ X,
    const float* __restrict__ Wbig, const float* __restrict__ bias_n,
    float* __restrict__ h_out, float* __restrict__ AX, float* __restrict__ bvec) {
    __shared__ __align__(16) float inT[64 * ET_PAD];
    __shared__ __align__(16) float Wl[64 * 64];
    const int t = threadIdx.x;
    const int m0 = blockIdx.x * 64, q = blockIdx.y, c0 = q * 64;
    const int tx = t & 15, ty = t >> 4;
    float acc[4][4] = {{0.f}};
    for (int h = 0; h < 2; ++h) {
        const float* P = h ? X : S;
        #pragma unroll
        for (int i = 0; i < 16; ++i) {
            int idx = i * 256 + t;
            int ml = idx >> 6, kl = idx & 63;
            int m = m0 + ml;
            inT[kl * ET_PAD + ml] = (m < N_NODES) ? P[(size_t)m * 64 + kl] : 0.f;
        }
        #pragma unroll
        for (int i = 0; i < 16; ++i) {
            int idx = i * 256 + t;
            int kl = idx >> 6, jl = idx & 63;
            Wl[kl * 64 + jl] = Wbig[(size_t)(h * 64 + kl) * 256 + c0 + jl];
        }
        __syncthreads();
        #pragma unroll 4
        for (int kl = 0; kl < 64; ++kl) {
            float4 av = *(const float4*)&inT[kl * ET_PAD + ty * 4];
            float4 wv = *(const float4*)&Wl[kl * 64 + tx * 4];
            float a4[4] = {av.x, av.y, av.z, av.w};
            float w4[4] = {wv.x, wv.y, wv.z, wv.w};
            #pragma unroll
            for (int im = 0; im < 4; ++im)
                #pragma unroll
                for (int ij = 0; ij < 4; ++ij)
                    acc[im][ij] = fmaf(a4[im], w4[ij], acc[im][ij]);
        }
        __syncthreads();
    }
    #pragma unroll
    for (int im = 0; im < 4; ++im) {
        int m = m0 + ty * 4 + im;
        if (m >= N_NODES) continue;
        #pragma unroll
        for (int ij = 0; ij < 4; ++ij) {
            int jl = tx * 4 + ij;
            float v = acc[im][ij];
            if (q == 0)      h_out[(size_t)m * 64 + jl] = v + bias_n[jl];
            else if (q == 1) AX[(size_t)m * 128 + 2 * jl] = v;
            else if (q == 2) bvec[(size_t)m * 64 + jl] = v;
            else             AX[(size_t)m * 128 + 2 * jl + 1] = v;
        }
    }
}

// --------------------------- counting sort by dst ---------------------------
__global__ void hist_k(const int* __restrict__ dst, int* __restrict__ counts) {
    int e = blockIdx.x * 256 + threadIdx.x;
    if (e < N_EDGES) atomicAdd(&counts[dst[e]], 1);
}

__global__ void scan1(const int* __restrict__ counts, int* __restrict__ bsum) {
    __shared__ int s[256];
    int t = threadIdx.x;
    int i = blockIdx.x * 256 + t;
    s[t] = (i < N_NODES) ? counts[i] : 0;
    __syncthreads();
    for (int off = 128; off > 0; off >>= 1) {
        if (t < off) s[t] += s[t + off];
        __syncthreads();
    }
    if (t == 0) bsum[blockIdx.x] = s[0];
}

__global__ void scan2(const int* __restrict__ bsum, int* __restrict__ boff) {
    __shared__ int s[256];
    int t = threadIdx.x;
    int v0 = (t < NB) ? bsum[t] : 0;
    s[t] = v0;
    __syncthreads();
    for (int off = 1; off < 256; off <<= 1) {
        int v = (t >= off) ? s[t - off] : 0;
        __syncthreads();
        s[t] += v;
        __syncthreads();
    }
    if (t < NB) boff[t] = s[t] - v0;  // exclusive
}

__global__ void scan3(const int* __restrict__ counts, const int* __restrict__ boff,
                      int* __restrict__ offsets, int* __restrict__ cursor) {
    __shared__ int s[256];
    int t = threadIdx.x;
    int i = blockIdx.x * 256 + t;
    int v0 = (i < N_NODES) ? counts[i] : 0;
    s[t] = v0;
    __syncthreads();
    for (int off = 1; off < 256; off <<= 1) {
        int v = (t >= off) ? s[t - off] : 0;
        __syncthreads();
        s[t] += v;
        __syncthreads();
    }
    int excl = s[t] - v0 + boff[blockIdx.x];
    if (i < N_NODES) { offsets[i] = excl; cursor[i] = excl; }
    if (i == N_NODES - 1) offsets[N_NODES] = excl + v0;
}

__global__ void scatter_k(const int* __restrict__ src, const int* __restrict__ dst,
                          int* __restrict__ cursor, int* __restrict__ perm,
                          int* __restrict__ sSrc, int* __restrict__ sDst) {
    int e = blockIdx.x * 256 + threadIdx.x;
    if (e < N_EDGES) {
        int d = dst[e];
        int p = atomicAdd(&cursor[d], 1);
        perm[p] = e;
        sSrc[p] = src[e];
        sDst[p] = d;
    }
}

// ---------------------------------------------------------------------------
// Edge pass over DST-SORTED positions. 64 edges/block, 256 threads.
// Thread (j = t&63, g = t>>6) handles 16 edges x 1 col. W1/WD read from
// global per-k (L1-resident 32 KB) -> LDS only 18 KB -> ~7 blocks/CU.
// hpre: per-thread run-accumulation over the sorted dst stream, then one
// atomic per run (~6.4M atomics vs 51.2M).
// ---------------------------------------------------------------------------
__global__ __launch_bounds__(256) void edge_kernel(
    const float* __restrict__ E, const int* __restrict__ perm,
    const int* __restrict__ sSrc, const int* __restrict__ sDst,
    const float* __restrict__ W1g /* w_e2e rows 0..63 */,
    const float* __restrict__ WDg,
    const float* __restrict__ AX, const float* __restrict__ bvec,
    const float* __restrict__ bias_e,
    float* __restrict__ e_out, float* __restrict__ hpre) {
    __shared__ int sPerm[64];
    __shared__ int sDstL[64];
    __shared__ __align__(16) float sEt[64 * ET_PAD];

    const int t = threadIdx.x;
    const int p0 = blockIdx.x * 64;
    if (t < 64) {
        sPerm[t] = perm[p0 + t];
        sDstL[t] = sDst[p0 + t];
    }
    __syncthreads();

    const int j = t & 63;
    const int g = t >> 6;

    float acc1[16], acc2[16];
    const float bj = bias_e[j];
    #pragma unroll
    for (int r = 0; r < 16; ++r) {
        int pos = g * 16 + r;
        int is = sSrc[p0 + pos];       // wave-uniform
        int id = sDstL[pos];
        float2 ax = *(const float2*)&AX[(size_t)is * 128 + 2 * j];
        acc1[r] = bj + ax.x + bvec[(size_t)id * 64 + j];
        acc2[r] = ax.y;
    }

    // stage E rows (perm-gathered, each row a contiguous 256 B read)
    #pragma unroll
    for (int i = 0; i < 16; ++i) {
        int idx = i * 256 + t;
        int r = idx >> 6, k = idx & 63;
        sEt[k * ET_PAD + r] = E[(size_t)sPerm[r] * 64 + k];
    }
    __syncthreads();

    #pragma unroll 4
    for (int k = 0; k < 64; ++k) {
        float w1 = W1g[k * 64 + j];
        float wd = WDg[k * 64 + j];
        const float4* ep = (const float4*)&sEt[k * ET_PAD + g * 16];
        #pragma unroll
        for (int q = 0; q < 4; ++q) {
            float4 ev = ep[q];
            acc1[4 * q + 0] = fmaf(ev.x, w1, acc1[4 * q + 0]);
            acc2[4 * q + 0] = fmaf(ev.x, wd, acc2[4 * q + 0]);
            acc1[4 * q + 1] = fmaf(ev.y, w1, acc1[4 * q + 1]);
            acc2[4 * q + 1] = fmaf(ev.y, wd, acc2[4 * q + 1]);
            acc1[4 * q + 2] = fmaf(ev.z, w1, acc1[4 * q + 2]);
            acc2[4 * q + 2] = fmaf(ev.z, wd, acc2[4 * q + 2]);
            acc1[4 * q + 3] = fmaf(ev.w, w1, acc1[4 * q + 3]);
            acc2[4 * q + 3] = fmaf(ev.w, wd, acc2[4 * q + 3]);
        }
    }

    // e_out scattered back to original edge ids (256 B chunks)
    #pragma unroll
    for (int r = 0; r < 16; ++r) {
        int e = sPerm[g * 16 + r];
        e_out[(size_t)e * 64 + j] = acc1[r];
    }

    // segmented reduction over sorted dst (branch is wave-uniform)
    int cur = sDstL[g * 16];
    float run = acc2[0];
    #pragma unroll
    for (int r = 1; r < 16; ++r) {
        int d = sDstL[g * 16 + r];
        if (d == cur) {
            run += acc2[r];
        } else {
            atomicAdd(&hpre[(size_t)cur * 64 + j], run);
            cur = d;
            run = acc2[r];
        }
    }
    atomicAdd(&hpre[(size_t)cur * 64 + j], run);
}

// ---------------------------------------------------------------------------
// Final: h_out += hpre / max(deg,1), deg from CSR offsets (no atomics).
// ---------------------------------------------------------------------------
__global__ void node_final(float* __restrict__ h_out,
                           const float* __restrict__ hpre,
                           const int* __restrict__ offsets) {
    int i = blockIdx.x * blockDim.x + threadIdx.x;
    if (i < N_NODES * 64) {
        int n = i >> 6;
        float deg = (float)(offsets[n + 1] - offsets[n]);
        float r = 1.0f / fmaxf(deg, 1.0f);
        h_out[i] += hpre[i] * r;
    }
}

extern "C" void kernel_launch(void* const* d_in, const int* in_sizes, int n_in,
                              void* d_out, int out_size, void* d_ws, size_t ws_size,
                              hipStream_t stream) {
    const float* S       = (const float*)d_in[0];
    const float* X       = (const float*)d_in[1];
    const float* E       = (const float*)d_in[2];
    const int*   src     = (const int*)  d_in[3];
    const int*   dst     = (const int*)  d_in[4];
    const float* w_n2n_u = (const float*)d_in[5];
    const float* w_n2n_v = (const float*)d_in[6];
    const float* w_e2n   = (const float*)d_in[7];
    const float* bias_n  = (const float*)d_in[8];
    const float* w_n2e_u = (const float*)d_in[9];
    const float* w_n2e_v = (const float*)d_in[10];
    const float* w_e2e   = (const float*)d_in[11];
    const float* bias_e  = (const float*)d_in[12];

    const size_t ND = (size_t)N_NODES * 64;   // 3,200,000

    float* ws        = (float*)d_ws;
    float* hpre      = ws;                                    // 3.2M f  (zeroed)
    int*   counts    = (int*)(ws + ND);                       // 50000   (zeroed)
    int*   offsets   = counts + N_NODES;                      // 50001
    int*   cursor    = offsets + N_NODES + 1;                 // 50000
    int*   bsum      = cursor + N_NODES;                      // 200
    int*   boff      = bsum + 200;                            // 200
    int*   perm      = boff + 200;                            // 800000
    int*   sSrc      = perm + N_EDGES;                        // 800000
    int*   sDst      = sSrc + N_EDGES;                        // 800000
    float* AX        = (float*)(sDst + N_EDGES);              // 6.4M f
    float* bvec      = AX + (size_t)N_NODES * 128;            // 3.2M f
    float* Wbig      = bvec + ND;                             // 32768 f
    float* WD        = Wbig + 128 * 256;                      // 4096 f

    float* h_out = (float*)d_out;
    float* e_out = h_out + ND;

    // zero hpre + counts (contiguous)
    hipMemsetAsync(hpre, 0, (ND + N_NODES) * sizeof(float), stream);

    fold_weights<<<576, 64, 0, stream>>>(w_n2n_u, w_n2n_v, w_e2n, w_n2e_u,
                                         w_n2e_v, nullptr, w_e2e, Wbig, WD);

    dim3 npGrid((N_NODES + 63) / 64, 4);
    node_pre<<<npGrid, 256, 0, stream>>>(S, X, Wbig, bias_n, h_out, AX, bvec);

    hist_k <<<(N_EDGES + 255) / 256, 256, 0, stream>>>(dst, counts);
    scan1  <<<NB, 256, 0, stream>>>(counts, bsum);
    scan2  <<<1, 256, 0, stream>>>(bsum, boff);
    scan3  <<<NB, 256, 0, stream>>>(counts, boff, offsets, cursor);
    scatter_k<<<(N_EDGES + 255) / 256, 256, 0, stream>>>(src, dst, cursor, perm, sSrc, sDst);

    edge_kernel<<<N_EDGES / 64, 256, 0, stream>>>(
        E, perm, sSrc, sDst, w_e2e, WD, AX, bvec, bias_e, e_out, hpre);

    node_final<<<(N_NODES * 64 + 255) / 256, 256, 0, stream>>>(h_out, hpre, offsets);
}

// Round 3
// 725.104 us; speedup vs baseline: 1.5194x; 1.0256x over previous
//
#include <hip/hip_runtime.h>

#define N_NODES 50000
#define N_EDGES 800000
#define D 64
#define ET_PAD 68   // node_pre LDS padding
#define NB 196      // ceil(50000/256) scan blocks

typedef __attribute__((ext_vector_type(8))) short short8;
typedef __attribute__((ext_vector_type(4))) float f32x4;

__device__ inline unsigned short f2bf(float f) {
    unsigned u = __float_as_uint(f);
    unsigned r = (u + 0x7FFFu + ((u >> 16) & 1u)) >> 16;
    return (unsigned short)r;
}

// ---------------------------------------------------------------------------
// Weight folding.
// Wbig[128][256] fp32 for node_pre GEMM [S|X]@Wbig:
//   cols 0..63 [Wv1;Wv2]->hbase, 64..127 [0;W_n2e_u@Ebot]->a,
//   128..191 [W_n2e_v@Ebot]->b, 192..255 [0;W_n2n_u@Wv3]->XC
// WTbf[128][64] bf16, B^T layout for the edge MFMA GEMM:
//   WTbf[n][k] = w_e2e[k][n] (n<64, ->e_out part), = WD[k][n-64] (n>=64, ->seg-sum part)
//   where WD = W_e2n@Wv3.  Ebot = w_e2e rows 64..127, Wv3 = w_n2n_v rows 128..191.
// ---------------------------------------------------------------------------
__global__ void fold_weights(const float* __restrict__ w_n2n_u,
                             const float* __restrict__ w_n2n_v,
                             const float* __restrict__ w_e2n,
                             const float* __restrict__ w_n2e_u,
                             const float* __restrict__ w_n2e_v,
                             const float* __restrict__ w_e2e,
                             float* __restrict__ Wbig,
                             unsigned short* __restrict__ WTbf) {
    int bidx = blockIdx.x;
    int j = threadIdx.x;
    const float* Ebot = w_e2e + 64 * 64;
    const float* Wv3  = w_n2n_v + 128 * 64;
    if (bidx < 512) {
        int k = bidx >> 2, q = bidx & 3;
        float v = 0.f;
        if (q == 0) {
            v = w_n2n_v[k * 64 + j];
        } else if (q == 1) {
            if (k >= 64) for (int t = 0; t < 64; ++t) v = fmaf(w_n2e_u[(k - 64) * 64 + t], Ebot[t * 64 + j], v);
        } else if (q == 2) {
            for (int t = 0; t < 64; ++t) v = fmaf(w_n2e_v[k * 64 + t], Ebot[t * 64 + j], v);
        } else {
            if (k >= 64) for (int t = 0; t < 64; ++t) v = fmaf(w_n2n_u[(k - 64) * 64 + t], Wv3[t * 64 + j], v);
        }
        Wbig[(size_t)k * 256 + q * 64 + j] = v;
    } else if (bidx < 576) {
        int k = bidx - 512;   // WD row k -> WTbf col-major scatter
        float v = 0.f;
        for (int t = 0; t < 64; ++t) v = fmaf(w_e2n[k * 64 + t], Wv3[t * 64 + j], v);
        WTbf[(64 + j) * 64 + k] = f2bf(v);
    } else {
        int k = bidx - 576;   // W1 row k
        WTbf[j * 64 + k] = f2bf(w_e2e[k * 64 + j]);
    }
}

// ---------------------------------------------------------------------------
// node_pre: out[50000x256] = [S|X] @ Wbig, fp32 register-tiled GEMM.
// q0 -> h_out (+bias_n), q1 -> AX[.,2j] (a), q2 -> bvec, q3 -> AX[.,2j+1] (XC)
// ---------------------------------------------------------------------------
__global__ __launch_bounds__(256) void node_pre(
    const float* __restrict__ S, const float* __restrict__ X,
    const float* __restrict__ Wbig, const float* __restrict__ bias_n,
    float* __restrict__ h_out, float* __restrict__ AX, float* __restrict__ bvec) {
    __shared__ __align__(16) float inT[64 * ET_PAD];
    __shared__ __align__(16) float Wl[64 * 64];
    const int t = threadIdx.x;
    const int m0 = blockIdx.x * 64, q = blockIdx.y, c0 = q * 64;
    const int tx = t & 15, ty = t >> 4;
    float acc[4][4] = {{0.f}};
    for (int h = 0; h < 2; ++h) {
        const float* P = h ? X : S;
        #pragma unroll
        for (int i = 0; i < 16; ++i) {
            int idx = i * 256 + t;
            int ml = idx >> 6, kl = idx & 63;
            int m = m0 + ml;
            inT[kl * ET_PAD + ml] = (m < N_NODES) ? P[(size_t)m * 64 + kl] : 0.f;
        }
        #pragma unroll
        for (int i = 0; i < 16; ++i) {
            int idx = i * 256 + t;
            int kl = idx >> 6, jl = idx & 63;
            Wl[kl * 64 + jl] = Wbig[(size_t)(h * 64 + kl) * 256 + c0 + jl];
        }
        __syncthreads();
        #pragma unroll 4
        for (int kl = 0; kl < 64; ++kl) {
            float4 av = *(const float4*)&inT[kl * ET_PAD + ty * 4];
            float4 wv = *(const float4*)&Wl[kl * 64 + tx * 4];
            float a4[4] = {av.x, av.y, av.z, av.w};
            float w4[4] = {wv.x, wv.y, wv.z, wv.w};
            #pragma unroll
            for (int im = 0; im < 4; ++im)
                #pragma unroll
                for (int ij = 0; ij < 4; ++ij)
                    acc[im][ij] = fmaf(a4[im], w4[ij], acc[im][ij]);
        }
        __syncthreads();
    }
    #pragma unroll
    for (int im = 0; im < 4; ++im) {
        int m = m0 + ty * 4 + im;
        if (m >= N_NODES) continue;
        #pragma unroll
        for (int ij = 0; ij < 4; ++ij) {
            int jl = tx * 4 + ij;
            float v = acc[im][ij];
            if (q == 0)      h_out[(size_t)m * 64 + jl] = v + bias_n[jl];
            else if (q == 1) AX[(size_t)m * 128 + 2 * jl] = v;
            else if (q == 2) bvec[(size_t)m * 64 + jl] = v;
            else             AX[(size_t)m * 128 + 2 * jl + 1] = v;
        }
    }
}

// --------------------------- counting sort by dst ---------------------------
__global__ void hist_k(const int* __restrict__ dst, int* __restrict__ counts) {
    int e = blockIdx.x * 256 + threadIdx.x;
    if (e < N_EDGES) atomicAdd(&counts[dst[e]], 1);
}

__global__ void scan1(const int* __restrict__ counts, int* __restrict__ bsum) {
    __shared__ int s[256];
    int t = threadIdx.x;
    int i = blockIdx.x * 256 + t;
    s[t] = (i < N_NODES) ? counts[i] : 0;
    __syncthreads();
    for (int off = 128; off > 0; off >>= 1) {
        if (t < off) s[t] += s[t + off];
        __syncthreads();
    }
    if (t == 0) bsum[blockIdx.x] = s[0];
}

__global__ void scan2(const int* __restrict__ bsum, int* __restrict__ boff) {
    __shared__ int s[256];
    int t = threadIdx.x;
    int v0 = (t < NB) ? bsum[t] : 0;
    s[t] = v0;
    __syncthreads();
    for (int off = 1; off < 256; off <<= 1) {
        int v = (t >= off) ? s[t - off] : 0;
        __syncthreads();
        s[t] += v;
        __syncthreads();
    }
    if (t < NB) boff[t] = s[t] - v0;  // exclusive
}

__global__ void scan3(const int* __restrict__ counts, const int* __restrict__ boff,
                      int* __restrict__ offsets, int* __restrict__ cursor) {
    __shared__ int s[256];
    int t = threadIdx.x;
    int i = blockIdx.x * 256 + t;
    int v0 = (i < N_NODES) ? counts[i] : 0;
    s[t] = v0;
    __syncthreads();
    for (int off = 1; off < 256; off <<= 1) {
        int v = (t >= off) ? s[t - off] : 0;
        __syncthreads();
        s[t] += v;
        __syncthreads();
    }
    int excl = s[t] - v0 + boff[blockIdx.x];
    if (i < N_NODES) { offsets[i] = excl; cursor[i] = excl; }
    if (i == N_NODES - 1) offsets[N_NODES] = excl + v0;
}

__global__ void scatter_k(const int* __restrict__ src, const int* __restrict__ dst,
                          int* __restrict__ cursor, int4* __restrict__ sEdge) {
    int e = blockIdx.x * 256 + threadIdx.x;
    if (e < N_EDGES) {
        int d = dst[e];
        int p = atomicAdd(&cursor[d], 1);
        sEdge[p] = make_int4(e, src[e], d, 0);
    }
}

// ---------------------------------------------------------------------------
// Edge pass (dst-sorted), bf16 MFMA. 64 edges/block, 4 waves, NO barriers:
// wave w owns edge rows 16w..16w+15 end-to-end (stage, MFMA, epilogue).
//   D[64x128] = Ebf16 @ [W1|WD]  via 8 n-tiles x 2 k-steps of 16x16x32 mfma
//   epilogue: e_out = D[:, :64] + a[src] + b[dst] + bias_e (scatter by perm)
//             hpre  += run-accumulated (D[:, 64:] + XC[src]) over sorted dst
// ---------------------------------------------------------------------------
__global__ __launch_bounds__(256) void edge_kernel(
    const float* __restrict__ E, const int4* __restrict__ sEdge,
    const unsigned short* __restrict__ WTbf,
    const float* __restrict__ AX, const float* __restrict__ bvec,
    const float* __restrict__ bias_e,
    float* __restrict__ e_out, float* __restrict__ hpre) {
    __shared__ __align__(16) unsigned short sEt[64 * 64];   // bf16 E tile, row-major
    __shared__ __align__(16) float sOut[64 * 128];          // D, cols interleaved (2j=W1, 2j+1=WD)

    const int t = threadIdx.x;
    const int lane = t & 63;
    const int w = t >> 6;
    const int p0 = blockIdx.x * 64;
    const int l15 = lane & 15, qd = lane >> 4;
    const int j = lane;  // epilogue output column

    // ---- prefetch gathers (random: issue earliest, overlap with MFMA) ----
    float2 axv[16];
    float  bv[16];
    int    permv[16], dstv[16];
    #pragma unroll
    for (int r = 0; r < 16; ++r) {
        int4 ed = sEdge[p0 + 16 * w + r];
        permv[r] = ed.x;
        dstv[r]  = ed.z;
        axv[r] = *(const float2*)&AX[(size_t)ed.y * 128 + 2 * j];
        bv[r]  = bvec[(size_t)ed.z * 64 + j];
    }

    // ---- stage this wave's 16 E rows as bf16 (f32x2 -> packed bf16x2) ----
    #pragma unroll
    for (int i = 0; i < 8; ++i) {
        int idx = i * 64 + lane;          // 0..511
        int r  = idx >> 5;                // 0..15
        int kp = idx & 31;                // f32-pair index
        int pe = sEdge[p0 + 16 * w + r].x;   // L1-hot reload
        float2 ev = *(const float2*)&E[(size_t)pe * 64 + 2 * kp];
        unsigned pk = ((unsigned)f2bf(ev.y) << 16) | (unsigned)f2bf(ev.x);
        *(unsigned*)&sEt[(16 * w + r) * 64 + 2 * kp] = pk;
    }

    // ---- MFMA: A row-major from LDS, B^T from global (L1-resident 16 KB) ----
    const short8 a0 = *(const short8*)&sEt[(16 * w + l15) * 64 +  0 + qd * 8];
    const short8 a1 = *(const short8*)&sEt[(16 * w + l15) * 64 + 32 + qd * 8];
    #pragma unroll
    for (int tt = 0; tt < 8; ++tt) {
        const short8 b0 = *(const short8*)&WTbf[(16 * tt + l15) * 64 +  0 + qd * 8];
        const short8 b1 = *(const short8*)&WTbf[(16 * tt + l15) * 64 + 32 + qd * 8];
        f32x4 d = {0.f, 0.f, 0.f, 0.f};
        d = __builtin_amdgcn_mfma_f32_16x16x32_bf16(a0, b0, d, 0, 0, 0);
        d = __builtin_amdgcn_mfma_f32_16x16x32_bf16(a1, b1, d, 0, 0, 0);
        // D layout: col n = l15 (out col 16*tt+l15), row m = qd*4+reg
        int colw = (tt < 4) ? (16 * tt + l15) : (16 * (tt - 4) + l15);
        int pos  = (tt < 4) ? (2 * colw) : (2 * colw + 1);
        #pragma unroll
        for (int reg = 0; reg < 4; ++reg)
            sOut[(16 * w + qd * 4 + reg) * 128 + pos] = d[reg];
    }

    // ---- epilogue: own rows only (intra-wave LDS dep, no barrier) ----
    const float bj = bias_e[j];
    float acc2[16];
    #pragma unroll
    for (int r = 0; r < 16; ++r) {
        float2 o = *(const float2*)&sOut[(16 * w + r) * 128 + 2 * j];
        float v1 = o.x + bj + axv[r].x + bv[r];
        acc2[r]  = o.y + axv[r].y;
        e_out[(size_t)permv[r] * 64 + j] = v1;   // coalesced 256B per row
    }

    // segmented reduction over sorted dst (wave-uniform branch)
    int cur = dstv[0];
    float run = acc2[0];
    #pragma unroll
    for (int r = 1; r < 16; ++r) {
        if (dstv[r] == cur) {
            run += acc2[r];
        } else {
            atomicAdd(&hpre[(size_t)cur * 64 + j], run);
            cur = dstv[r];
            run = acc2[r];
        }
    }
    atomicAdd(&hpre[(size_t)cur * 64 + j], run);
}

// ---------------------------------------------------------------------------
// Final: h_out += hpre / max(deg,1), deg from CSR offsets.
// ---------------------------------------------------------------------------
__global__ void node_final(float* __restrict__ h_out,
                           const float* __restrict__ hpre,
                           const int* __restrict__ offsets) {
    int i = blockIdx.x * blockDim.x + threadIdx.x;
    if (i < N_NODES * 64) {
        int n = i >> 6;
        float deg = (float)(offsets[n + 1] - offsets[n]);
        float r = 1.0f / fmaxf(deg, 1.0f);
        h_out[i] += hpre[i] * r;
    }
}

extern "C" void kernel_launch(void* const* d_in, const int* in_sizes, int n_in,
                              void* d_out, int out_size, void* d_ws, size_t ws_size,
                              hipStream_t stream) {
    const float* S       = (const float*)d_in[0];
    const float* X       = (const float*)d_in[1];
    const float* E       = (const float*)d_in[2];
    const int*   src     = (const int*)  d_in[3];
    const int*   dst     = (const int*)  d_in[4];
    const float* w_n2n_u = (const float*)d_in[5];
    const float* w_n2n_v = (const float*)d_in[6];
    const float* w_e2n   = (const float*)d_in[7];
    const float* bias_n  = (const float*)d_in[8];
    const float* w_n2e_u = (const float*)d_in[9];
    const float* w_n2e_v = (const float*)d_in[10];
    const float* w_e2e   = (const float*)d_in[11];
    const float* bias_e  = (const float*)d_in[12];

    const size_t ND = (size_t)N_NODES * 64;   // 3,200,000

    float* ws = (float*)d_ws;
    float*          hpre    = ws;                                   // 3.2M f (zeroed)
    float*          AX      = ws + ND;                              // 6.4M f
    float*          bvec    = AX + (size_t)N_NODES * 128;           // 3.2M f
    float*          Wbig    = bvec + ND;                            // 32768 f
    unsigned short* WTbf    = (unsigned short*)(Wbig + 128 * 256);  // 8192 u16
    int*            counts  = (int*)(WTbf + 8192);                  // 50000 (zeroed)
    int4*           sEdge   = (int4*)(counts + N_NODES);            // 800000 int4 (16B-aligned)
    int*            offsets = (int*)(sEdge + N_EDGES);              // 50001
    int*            cursor  = offsets + N_NODES + 1;                // 50000
    int*            bsum    = cursor + N_NODES;                     // 200
    int*            boff    = bsum + 200;                           // 200

    float* h_out = (float*)d_out;
    float* e_out = h_out + ND;

    hipMemsetAsync(hpre, 0, ND * sizeof(float), stream);
    hipMemsetAsync(counts, 0, N_NODES * sizeof(int), stream);

    fold_weights<<<640, 64, 0, stream>>>(w_n2n_u, w_n2n_v, w_e2n, w_n2e_u,
                                         w_n2e_v, w_e2e, Wbig, WTbf);

    dim3 npGrid((N_NODES + 63) / 64, 4);
    node_pre<<<npGrid, 256, 0, stream>>>(S, X, Wbig, bias_n, h_out, AX, bvec);

    hist_k <<<(N_EDGES + 255) / 256, 256, 0, stream>>>(dst, counts);
    scan1  <<<NB, 256, 0, stream>>>(counts, bsum);
    scan2  <<<1, 256, 0, stream>>>(bsum, boff);
    scan3  <<<NB, 256, 0, stream>>>(counts, boff, offsets, cursor);
    scatter_k<<<(N_EDGES + 255) / 256, 256, 0, stream>>>(src, dst, cursor, sEdge);

    edge_kernel<<<N_EDGES / 64, 256, 0, stream>>>(
        E, sEdge, WTbf, AX, bvec, bias_e, e_out, hpre);

    node_final<<<(N_NODES * 64 + 255) / 256, 256, 0, stream>>>(h_out, hpre, offsets);
}